// Round 1
// baseline (579.880 us; speedup 1.0000x reference)
//
#include <hip/hip_runtime.h>

// Problem constants (from reference)
#define C_IN  8
#define H     32
#define W     32
#define C_OUT 16
#define KH    3
#define KW    3
#define OH    32
#define OW    32
#define N_IN  (C_IN * H * W)     // 8192
#define N_OUT (C_OUT * OH * OW)  // 16384
#define MROWS (N_IN + 1)         // 8193
#define MCOLS (N_OUT + 1)        // 16385

typedef float v4f __attribute__((ext_vector_type(4)));

// Block roles:
//   [0, NB_SCATTER)                    : one thread per (row, oc, di, dj) nonzero candidate
//   [NB_SCATTER, NB_SCATTER+NB_BIAS)   : bias row (row 8192), one block per channel
//   [.., +NB_BOUNDS)                   : interval bounds lo/hi
// The bulk zeros of M are produced by hipMemsetAsync BEFORE this kernel (same
// stream, so graph order is preserved): the rocclr fill kernel sustains
// 6.19 TB/s on this chip (measured on the harness poison fill), which a
// hand-rolled screened fill loop could not match (~2.7 TB/s).
#define NB_SCATTER 4608          // 4608*256 = 1,179,648 = 8192 rows * 144 taps
#define NB_BIAS    16
#define NB_BOUNDS  64

__global__ __launch_bounds__(256) void scatter_kernel(const float* __restrict__ l_in,
                                                      const float* __restrict__ u_in,
                                                      const float* __restrict__ wts,
                                                      const float* __restrict__ bias,
                                                      float* __restrict__ out,
                                                      float* __restrict__ M) {
    const int b = blockIdx.x;
    const int t = threadIdx.x;

    if (b < NB_SCATTER) {
        // ---------------- nonzero scatter ----------------
        // tid enumerates (r, oc, di, dj): r = input neuron (cin, iy, ix),
        // di/dj = output-pixel offset within the 3x3 neighborhood.
        // Mapping (verified against reference build_abstract_matrix):
        //   i = iy-1+di, j = ix-1+dj, kh = 2-di, kw = 2-dj
        //   => idy = i-1+kh = iy, idx = j-1+kw = ix  (row matches), and
        //   M[r][oc*1024 + i*32 + j] = w[oc][cin][kh][kw].
        // Each (r,c) nonzero is written by exactly one thread; all other
        // entries stay at the memset's 0.
        const int tid = (b << 8) + t;          // 0 .. 1,179,647
        const int r   = tid / 144;             // input neuron index
        const int k   = tid - r * 144;         // 0..143
        const int oc  = k / 9;
        const int q   = k - oc * 9;
        const int di  = q / 3;
        const int dj  = q - di * 3;

        const int cin = r >> 10;
        const int iy  = (r >> 5) & 31;
        const int ix  = r & 31;

        const int i = iy - 1 + di;
        const int j = ix - 1 + dj;

        if (((unsigned)i < 32u) & ((unsigned)j < 32u)) {
            const int kh = 2 - di;
            const int kw = 2 - dj;
            const float w = wts[oc * 72 + cin * 9 + kh * 3 + kw];
            M[(size_t)r * MCOLS + (oc << 10) + (i << 5) + j] = w;
        }
        return;
    }

    if (b < NB_SCATTER + NB_BIAS) {
        // ---------------- bias row (row 8192) ----------------
        // One block per output channel: 1024 contiguous floats, 4 per thread.
        const int bb = b - NB_SCATTER;                 // 0..15 == channel
        float* __restrict__ Mrow = M + (size_t)N_IN * MCOLS;
        const float bv = bias[bb];
        v4f v = {bv, bv, bv, bv};
        *(v4f*)(Mrow + (bb << 10) + 4 * t) = v;        // 16B-aligned (row start aligned)
        if (bb == 0 && t == 0) Mrow[N_OUT] = 1.0f;     // homogeneous corner
        return;
    }

    // ---------------- interval bounds (unchanged from passing kernel) ------
    int tid = (b - (NB_SCATTER + NB_BIAS)) * 256 + t;
    int c = tid >> 10;
    int i = (tid >> 5) & 31;
    int j = tid & 31;

    float lo = bias[c];
    float hi = lo;

    #pragma unroll
    for (int cin = 0; cin < C_IN; ++cin) {
        #pragma unroll
        for (int kh = 0; kh < KH; ++kh) {
            int iy = i - 1 + kh;
            if ((unsigned)iy >= (unsigned)H) continue;
            #pragma unroll
            for (int kw = 0; kw < KW; ++kw) {
                int ix = j - 1 + kw;
                if ((unsigned)ix >= (unsigned)W) continue;
                float w = wts[c * 72 + cin * 9 + kh * 3 + kw];
                int   r = cin * 1024 + iy * 32 + ix;
                float a  = w * l_in[r];
                float bb = w * u_in[r];
                lo += fminf(a, bb);
                hi += fmaxf(a, bb);
            }
        }
    }
    out[tid]         = lo;
    out[N_OUT + tid] = hi;
}

extern "C" void kernel_launch(void* const* d_in, const int* in_sizes, int n_in,
                              void* d_out, int out_size, void* d_ws, size_t ws_size,
                              hipStream_t stream) {
    const float* lower = (const float*)d_in[0];
    const float* upper = (const float*)d_in[1];
    const float* wts   = (const float*)d_in[2];
    const float* bias  = (const float*)d_in[3];

    float* out = (float*)d_out;
    float* M   = out + 2 * N_OUT;   // lo(16384) | hi(16384) | M(8193*16385)

    // Zero the entire M region at the runtime fill's measured 6.19 TB/s
    // (~87 us for 537 MB). lo/hi are fully written by the bounds blocks, so
    // they need no clearing. Memset nodes are graph-capturable.
    hipMemsetAsync(M, 0, (size_t)MROWS * MCOLS * sizeof(float), stream);

    const int grid = NB_SCATTER + NB_BIAS + NB_BOUNDS;   // 4608 + 16 + 64 = 4688
    hipLaunchKernelGGL(scatter_kernel, dim3(grid), dim3(256), 0, stream,
                       lower, upper, wts, bias, out, M);
}

// Round 2
// 544.299 us; speedup vs baseline: 1.0654x; 1.0654x over previous
//
#include <hip/hip_runtime.h>

// Problem constants (from reference)
#define C_IN  8
#define H     32
#define W     32
#define C_OUT 16
#define KH    3
#define KW    3
#define OH    32
#define OW    32
#define N_IN  (C_IN * H * W)     // 8192
#define N_OUT (C_OUT * OH * OW)  // 16384
#define MROWS (N_IN + 1)         // 8193
#define MCOLS (N_OUT + 1)        // 16385

typedef float v4f __attribute__((ext_vector_type(4)));

// Grid layout (single kernel, single dispatch — no memset node):
//   b == 0           : bias row (row 8192)
//   b in [1, 65)     : interval bounds lo/hi (64 blocks)
//   b in [65, 8257)  : one block per M-row r = b-65:
//                        step 1: unrolled v4f zero-fill of the whole row
//                                (64 KB contiguous, no screening arithmetic,
//                                 runs at rocclr-fill rate)
//                        __syncthreads()
//                        step 2: threads 0..143 overwrite the row's <=144
//                                nonzeros. Lines are still dirty in this
//                                XCD's L2 (just written by this block), so
//                                these 4B stores cost no HBM RMW.
// Round-1 lesson: a separate scatter dispatch after a 537 MB memset hits
// cold lines (L2 fully cycled) -> every 4B store becomes an HBM
// read-modify-write, plus a serialization bubble. Fusing scatter into the
// fill block removes both.
#define NB_PRE   65
#define NB_ROWS  8192

__global__ __launch_bounds__(256) void fused_kernel(const float* __restrict__ l_in,
                                                    const float* __restrict__ u_in,
                                                    const float* __restrict__ wts,
                                                    const float* __restrict__ bias,
                                                    float* __restrict__ out,
                                                    float* __restrict__ M) {
    const int b = blockIdx.x;
    const int t = threadIdx.x;

    if (b >= NB_PRE) {
        // ---------------- row fill + in-block scatter ----------------
        const int r = b - NB_PRE;                       // 0..8191
        const size_t base = (size_t)r * MCOLS;          // word index of row start
        float* __restrict__ rowp = M + base;

        // --- pre-compute this thread's nonzero (if any); load weight early so
        //     its latency hides under the fill stores ---
        const int iy  = (r >> 5) & 31;
        const int ix  = r & 31;
        const int cin = r >> 10;
        bool   ok = false;
        float  wv = 0.0f;
        int    col = 0;
        if (t < 144) {
            const int oc = t / 9;                       // 0..15
            const int q  = t - oc * 9;                  // 0..8
            const int di = q / 3;
            const int dj = q - di * 3;
            const int i  = iy - 1 + di;                 // output row
            const int j  = ix - 1 + dj;                 // output col
            ok = ((unsigned)i < 32u) & ((unsigned)j < 32u);
            if (ok) {
                const int kh = 2 - di;
                const int kw = 2 - dj;
                wv  = wts[oc * 72 + cin * 9 + kh * 3 + kw];
                col = (oc << 10) + (i << 5) + j;
            }
        }

        // --- step 1: zero-fill the row (16385 words, head/body/tail for
        //     16B alignment: row start drifts by r mod 4 words) ---
        const int mis = (int)(base & 3);
        const int a   = (4 - mis) & 3;                  // head words
        if (t < a) rowp[t] = 0.0f;

        const int nwords = MCOLS - a;                   // 16382..16385
        const int nspans = nwords >> 2;                 // 4095 or 4096
        const int ntail  = nwords & 3;
        float* __restrict__ bodyp = rowp + a;           // 16B aligned
        const v4f zero = {0.0f, 0.0f, 0.0f, 0.0f};

        // 15 always-valid spans per thread + 1 predicated (nspans >= 4095,
        // t + 14*256 <= 3839 < 4095 always valid).
        #pragma unroll
        for (int k = 0; k < 15; ++k)
            *(v4f*)(bodyp + 4 * (t + 256 * k)) = zero;
        if (t + 3840 < nspans)
            *(v4f*)(bodyp + 4 * (t + 3840)) = zero;

        if (t < ntail) bodyp[4 * nspans + t] = 0.0f;

        __syncthreads();

        // --- step 2: scatter the nonzeros (lines are L2-hot) ---
        if (ok) rowp[col] = wv;
        return;
    }

    if (b == 0) {
        // ---------------- bias row (row 8192; word base is 16B aligned) -----
        float* __restrict__ Mrow = M + (size_t)N_IN * MCOLS;
        #pragma unroll
        for (int k = 0; k < 16; ++k) {
            const float bv = bias[k];                   // word (k<<10)+4t -> channel k
            v4f v = {bv, bv, bv, bv};
            *(v4f*)(Mrow + (k << 10) + 4 * t) = v;
        }
        if (t == 0) Mrow[N_OUT] = 1.0f;
        return;
    }

    // ---------------- interval bounds (unchanged, verified) ----------------
    int tid = (b - 1) * 256 + t;
    int c = tid >> 10;
    int i = (tid >> 5) & 31;
    int j = tid & 31;

    float lo = bias[c];
    float hi = lo;

    #pragma unroll
    for (int cin = 0; cin < C_IN; ++cin) {
        #pragma unroll
        for (int kh = 0; kh < KH; ++kh) {
            int iy = i - 1 + kh;
            if ((unsigned)iy >= (unsigned)H) continue;
            #pragma unroll
            for (int kw = 0; kw < KW; ++kw) {
                int ix = j - 1 + kw;
                if ((unsigned)ix >= (unsigned)W) continue;
                float w = wts[c * 72 + cin * 9 + kh * 3 + kw];
                int   r = cin * 1024 + iy * 32 + ix;
                float a  = w * l_in[r];
                float bb = w * u_in[r];
                lo += fminf(a, bb);
                hi += fmaxf(a, bb);
            }
        }
    }
    out[tid]         = lo;
    out[N_OUT + tid] = hi;
}

extern "C" void kernel_launch(void* const* d_in, const int* in_sizes, int n_in,
                              void* d_out, int out_size, void* d_ws, size_t ws_size,
                              hipStream_t stream) {
    const float* lower = (const float*)d_in[0];
    const float* upper = (const float*)d_in[1];
    const float* wts   = (const float*)d_in[2];
    const float* bias  = (const float*)d_in[3];

    float* out = (float*)d_out;
    float* M   = out + 2 * N_OUT;   // lo(16384) | hi(16384) | M(8193*16385)

    const int grid = NB_PRE + NB_ROWS;   // 65 + 8192 = 8257
    hipLaunchKernelGGL(fused_kernel, dim3(grid), dim3(256), 0, stream,
                       lower, upper, wts, bias, out, M);
}